// Round 1
// baseline (623.179 us; speedup 1.0000x reference)
//
#include <hip/hip_runtime.h>

#define DM 64
#define OO 256
#define LL 16
#define BB 32
#define NSEQ (BB*OO)       // 8192
#define NROWS (BB*LL*OO)   // 131072

// ---------------- Kernel A: geo path (tiny) ----------------
// grid 256 (one per o-row), 256 threads.
// attn = softmax(-dis[o,:]); fg = attn @ E; gz[o][j] = bi[j]+bh[j]+sum_d fg[d]*Wi[j][64+d]
__global__ __launch_bounds__(256) void geo_kernel(const float* __restrict__ dis,
                                                  const float* __restrict__ E,
                                                  const float* __restrict__ Wi,
                                                  const float* __restrict__ bi,
                                                  const float* __restrict__ bh,
                                                  float* __restrict__ gz)
{
    __shared__ float attn[OO];
    __shared__ float fg[DM];
    __shared__ float red[256];
    int o = blockIdx.x, t = threadIdx.x;
    float x = -dis[o*OO + t];
    red[t] = x; __syncthreads();
    for (int s = 128; s > 0; s >>= 1) { if (t < s) red[t] = fmaxf(red[t], red[t+s]); __syncthreads(); }
    float mx = red[0]; __syncthreads();
    float e = __expf(x - mx);
    red[t] = e; __syncthreads();
    for (int s = 128; s > 0; s >>= 1) { if (t < s) red[t] += red[t+s]; __syncthreads(); }
    float inv = 1.0f / red[0];
    attn[t] = e * inv;
    __syncthreads();
    if (t < DM) {
        float acc = 0.f;
        for (int j = 0; j < OO; ++j) acc += attn[j] * E[j*DM + t];
        fg[t] = acc;
    }
    __syncthreads();
    float acc = bi[t] + bh[t];
    #pragma unroll
    for (int d = 0; d < DM; ++d) acc += fg[d] * Wi[t*2*DM + DM + d];
    gz[o*OO + t] = acc;
}

// ---------------- Kernel B: ff = X @ E ----------------
// grid 512, 256 threads; block computes 256 rows x 64 cols, K=256.
// E operands are wave-uniform -> scalar loads; X chunk transposed in LDS (conflict-free).
__global__ __launch_bounds__(256) void ff_kernel(const float* __restrict__ X,
                                                 const float* __restrict__ E,
                                                 float* __restrict__ ff)
{
    __shared__ float Xt[64][256];   // 64 KB, transposed chunk
    long rbase = (long)blockIdx.x * 256;
    int t = threadIdx.x;
    float acc[DM];
    #pragma unroll
    for (int d = 0; d < DM; ++d) acc[d] = 0.f;
    for (int kc = 0; kc < 4; ++kc) {
        __syncthreads();
        const float4* X4 = (const float4*)(X + rbase*256 + kc*64);
        #pragma unroll
        for (int i = 0; i < 16; ++i) {
            float4 v = X4[(long)t*64 + i];      // row t, float4 i of this k-chunk
            Xt[i*4+0][t] = v.x; Xt[i*4+1][t] = v.y; Xt[i*4+2][t] = v.z; Xt[i*4+3][t] = v.w;
        }
        __syncthreads();
        const float* Ek = E + kc*64*DM;
        for (int k = 0; k < 64; ++k) {
            float xv = Xt[k][t];
            const float* Er = Ek + k*DM;        // uniform across wave -> s_load
            #pragma unroll
            for (int d = 0; d < DM; ++d) acc[d] += xv * Er[d];
        }
    }
    float4* out4 = (float4*)(ff + (rbase + t)*DM);
    #pragma unroll
    for (int i = 0; i < 16; ++i)
        out4[i] = make_float4(acc[4*i], acc[4*i+1], acc[4*i+2], acc[4*i+3]);
}

// ---------------- Kernel C: LSTM (fused input+recurrent GEMM) ----------------
// grid 2048, 256 threads; block owns 4 sequences (same b, 4 consecutive o).
// Thread t owns z-column j=t (weights Wi1[j][:], Wh[j][:] in VGPRs) for phase 1,
// and cell (s=t>>6, d=t&63) for phase 2 (c in a register across steps).
__global__ __launch_bounds__(256) void lstm_kernel(const float* __restrict__ ff,
                                                   const float* __restrict__ gz,
                                                   const float* __restrict__ Wi,
                                                   const float* __restrict__ Wh,
                                                   float* __restrict__ h_last,
                                                   float* __restrict__ hsum,
                                                   float* __restrict__ hsq)
{
    __shared__ __align__(16) float h_lds[4*DM];
    __shared__ __align__(16) float ff_lds[4*DM];
    __shared__ __align__(16) float z_lds[4*OO];
    int t = threadIdx.x;
    int bo_base = blockIdx.x * 4;
    int b = bo_base >> 8;
    int o_base = bo_base & 255;

    float wi[DM], wh[DM];
    #pragma unroll
    for (int d = 0; d < DM; ++d) wi[d] = Wi[t*128 + d];
    #pragma unroll
    for (int d = 0; d < DM; ++d) wh[d] = Wh[t*DM + d];
    float gzr[4];
    #pragma unroll
    for (int s = 0; s < 4; ++s) gzr[s] = gz[(o_base + s)*OO + t];

    h_lds[t] = 0.f;
    float c = 0.f;
    float sum_r = 0.f, sq_r = 0.f;
    int s2 = t >> 6, d2 = t & 63;

    for (int step = 0; step < LL; ++step) {
        float ffv = ff[(((long)(b*LL + step))*OO + o_base)*DM + t];
        __syncthreads();            // prev phase-2 done (h_lds final, z_lds consumed)
        ff_lds[t] = ffv;
        __syncthreads();
        // phase 1: z[s][t]
        #pragma unroll
        for (int s = 0; s < 4; ++s) {
            float z = gzr[s];
            const float4* f4 = (const float4*)&ff_lds[s*DM];
            const float4* h4 = (const float4*)&h_lds[s*DM];
            #pragma unroll
            for (int k4 = 0; k4 < 16; ++k4) {
                float4 fv = f4[k4];
                z += fv.x*wi[4*k4] + fv.y*wi[4*k4+1] + fv.z*wi[4*k4+2] + fv.w*wi[4*k4+3];
                float4 hv = h4[k4];
                z += hv.x*wh[4*k4] + hv.y*wh[4*k4+1] + hv.z*wh[4*k4+2] + hv.w*wh[4*k4+3];
            }
            z_lds[s*OO + t] = z;
        }
        __syncthreads();
        // phase 2: gates for cell (s2, d2)
        float zi = z_lds[s2*OO + d2];
        float zf = z_lds[s2*OO + 64 + d2];
        float zg = z_lds[s2*OO + 128 + d2];
        float zo = z_lds[s2*OO + 192 + d2];
        float ig  = 1.f/(1.f + __expf(-zi));
        float fgg = 1.f/(1.f + __expf(-zf));
        float gg  = tanhf(zg);
        float og  = 1.f/(1.f + __expf(-zo));
        c = fgg*c + ig*gg;
        float h = og * tanhf(c);
        h_lds[s2*DM + d2] = h;
        sum_r += h; sq_r += h*h;
        if (step == LL-1) h_last[(bo_base + s2)*DM + d2] = h;
    }
    // channel-sum reduction -> atomics
    __syncthreads();
    z_lds[t] = sum_r; z_lds[256 + t] = sq_r;
    __syncthreads();
    if (t < DM) {
        float s0 = z_lds[t] + z_lds[64+t] + z_lds[128+t] + z_lds[192+t];
        float q0 = z_lds[256+t] + z_lds[256+64+t] + z_lds[256+128+t] + z_lds[256+192+t];
        atomicAdd(&hsum[t], s0);
        atomicAdd(&hsq[t], q0);
    }
}

// ---------------- Kernel D: LayerNorm params + v + lv + out ----------------
// grid 512 (b = blk>>4, og = blk&15), 256 threads; block computes 16 o-rows x 256 cols of out[b].
__global__ __launch_bounds__(256) void final_kernel(const float* __restrict__ h_last,
                                                    const float* __restrict__ hsum,
                                                    const float* __restrict__ hsq,
                                                    const float* __restrict__ gamma,
                                                    const float* __restrict__ beta,
                                                    const float* __restrict__ Wl,
                                                    const float* __restrict__ bl,
                                                    float* __restrict__ out)
{
    __shared__ float vlds[OO][DM+1];   // +1 pad: conflict-free column reads
    __shared__ float lv[16][DM];
    __shared__ float mrs[2][DM];
    int t = threadIdx.x;
    int b = blockIdx.x >> 4, og = blockIdx.x & 15;
    if (t < DM) {
        float m = hsum[t] * (1.0f/131072.0f);
        float var = hsq[t] * (1.0f/131072.0f) - m*m;
        mrs[0][t] = m;
        mrs[1][t] = rsqrtf(var + 1e-5f) * gamma[t];
    }
    __syncthreads();
    const float4* hb = (const float4*)(h_last + (long)b*OO*DM);
    #pragma unroll
    for (int i = 0; i < 16; ++i) {
        int f4 = i*256 + t;
        float4 v = hb[f4];
        int o = f4 >> 4;
        int d = (f4 & 15) * 4;
        vlds[o][d]   = (v.x - mrs[0][d])   * mrs[1][d]   + beta[d];
        vlds[o][d+1] = (v.y - mrs[0][d+1]) * mrs[1][d+1] + beta[d+1];
        vlds[o][d+2] = (v.z - mrs[0][d+2]) * mrs[1][d+2] + beta[d+2];
        vlds[o][d+3] = (v.w - mrs[0][d+3]) * mrs[1][d+3] + beta[d+3];
    }
    __syncthreads();
    {   // lv rows for this block's 16 o-rows
        int oo = t >> 4;
        int e0 = (t & 15) * 4;
        int o = og*16 + oo;
        float a0 = bl[e0], a1 = bl[e0+1], a2 = bl[e0+2], a3 = bl[e0+3];
        #pragma unroll
        for (int f = 0; f < DM; ++f) {
            float vv = vlds[o][f];
            a0 += vv * Wl[(e0  )*DM + f];
            a1 += vv * Wl[(e0+1)*DM + f];
            a2 += vv * Wl[(e0+2)*DM + f];
            a3 += vv * Wl[(e0+3)*DM + f];
        }
        lv[oo][e0] = a0; lv[oo][e0+1] = a1; lv[oo][e0+2] = a2; lv[oo][e0+3] = a3;
    }
    __syncthreads();
    float* ob = out + ((long)b*OO + og*16)*OO;
    #pragma unroll
    for (int oo = 0; oo < 16; ++oo) {
        float acc = 0.f;
        #pragma unroll
        for (int e = 0; e < DM; ++e) acc += lv[oo][e] * vlds[t][e];
        ob[oo*OO + t] = acc;
    }
}

extern "C" void kernel_launch(void* const* d_in, const int* in_sizes, int n_in,
                              void* d_out, int out_size, void* d_ws, size_t ws_size,
                              hipStream_t stream) {
    const float* X     = (const float*)d_in[0];
    const float* dis   = (const float*)d_in[1];
    const float* E     = (const float*)d_in[2];
    const float* Wi    = (const float*)d_in[3];
    const float* Wh    = (const float*)d_in[4];
    const float* bi    = (const float*)d_in[5];
    const float* bh    = (const float*)d_in[6];
    const float* gamma = (const float*)d_in[7];
    const float* beta  = (const float*)d_in[8];
    const float* Wl    = (const float*)d_in[9];
    const float* bl    = (const float*)d_in[10];
    float* out = (float*)d_out;

    char* ws = (char*)d_ws;
    float* gz   = (float*)(ws);                               // 256*256*4      = 256 KB
    float* ff   = (float*)(ws + 262144);                      // 131072*64*4    = 33.5 MB
    float* hl   = (float*)(ws + 262144 + 33554432);           // 8192*64*4      = 2 MB
    float* hsum = (float*)(ws + 262144 + 33554432 + 2097152); // 64
    float* hsq  = hsum + 64;                                  // 64

    hipMemsetAsync(hsum, 0, 2*64*sizeof(float), stream);
    geo_kernel<<<256, 256, 0, stream>>>(dis, E, Wi, bi, bh, gz);
    ff_kernel<<<512, 256, 0, stream>>>(X, E, ff);
    lstm_kernel<<<2048, 256, 0, stream>>>(ff, gz, Wi, Wh, hl, hsum, hsq);
    final_kernel<<<512, 256, 0, stream>>>(hl, hsum, hsq, gamma, beta, Wl, bl, out);
}

// Round 2
// 456.017 us; speedup vs baseline: 1.3666x; 1.3666x over previous
//
#include <hip/hip_runtime.h>

#define DM 64
#define OO 256
#define LL 16
#define BB 32

__device__ __forceinline__ float sigmoid_f(float x) {
    return __builtin_amdgcn_rcpf(1.f + __expf(-x));
}
__device__ __forceinline__ float tanh_f(float x) {
    // tanh(x) = 2/(1+exp(-2x)) - 1
    return 2.f * __builtin_amdgcn_rcpf(1.f + __expf(-2.f * x)) - 1.f;
}

// ---------------- Kernel A: geo path ----------------
// grid 256, 256 threads. attn=softmax(-dis[o,:]); fg=attn@E; gz[o][j]=bi+bh+sum_d fg[d]*Wi[j][64+d]
__global__ __launch_bounds__(256) void geo_kernel(const float* __restrict__ dis,
                                                  const float* __restrict__ E,
                                                  const float* __restrict__ Wi,
                                                  const float* __restrict__ bi,
                                                  const float* __restrict__ bh,
                                                  float* __restrict__ gz)
{
    __shared__ float attn[OO];
    __shared__ float red[256];
    __shared__ float fgp[4][DM];
    __shared__ float fg[DM];
    int o = blockIdx.x, t = threadIdx.x;
    float x = -dis[o*OO + t];
    red[t] = x; __syncthreads();
    for (int s = 128; s > 0; s >>= 1) { if (t < s) red[t] = fmaxf(red[t], red[t+s]); __syncthreads(); }
    float mx = red[0]; __syncthreads();
    float e = __expf(x - mx);
    red[t] = e; __syncthreads();
    for (int s = 128; s > 0; s >>= 1) { if (t < s) red[t] += red[t+s]; __syncthreads(); }
    float inv = __builtin_amdgcn_rcpf(red[0]);
    attn[t] = e * inv;
    __syncthreads();
    // fg partials: thread (d = t&63, jq = t>>6) sums j in [jq*64, jq*64+64)
    {
        int d = t & 63, jq = t >> 6;
        float a = 0.f;
        #pragma unroll 4
        for (int j = 0; j < 64; ++j) a += attn[jq*64 + j] * E[(jq*64 + j)*DM + d];
        fgp[jq][d] = a;
    }
    __syncthreads();
    if (t < DM) fg[t] = fgp[0][t] + fgp[1][t] + fgp[2][t] + fgp[3][t];
    __syncthreads();
    float acc = bi[t] + bh[t];
    const float4* f4 = (const float4*)fg;
    const float4* w4 = (const float4*)(Wi + t*2*DM + DM);
    #pragma unroll
    for (int q = 0; q < 16; ++q) {
        float4 fv = f4[q]; float4 wv = w4[q];
        acc += fv.x*wv.x + fv.y*wv.y + fv.z*wv.z + fv.w*wv.w;
    }
    gz[o*OO + t] = acc;
}

// ---------------- Kernel B: ff = X @ E ----------------
// grid 512, 256 threads; block computes 256 rows x 64 cols, K=256.
__global__ __launch_bounds__(256) void ff_kernel(const float* __restrict__ X,
                                                 const float* __restrict__ E,
                                                 float* __restrict__ ff)
{
    __shared__ float Xt[64][257];   // transposed chunk, +1 pad
    long rbase = (long)blockIdx.x * 256;
    int t = threadIdx.x;
    float acc[DM];
    #pragma unroll
    for (int d = 0; d < DM; ++d) acc[d] = 0.f;
    for (int kc = 0; kc < 4; ++kc) {
        __syncthreads();
        const float4* X4 = (const float4*)(X + rbase*256 + kc*64);
        #pragma unroll
        for (int i = 0; i < 16; ++i) {
            int f = i*256 + t;          // flat float4 index: row r, col-quad c4
            int r = f >> 4, c4 = f & 15;
            float4 v = X4[(long)r*64 + c4];   // lanes contiguous -> coalesced 4KB/instr
            Xt[c4*4+0][r] = v.x; Xt[c4*4+1][r] = v.y; Xt[c4*4+2][r] = v.z; Xt[c4*4+3][r] = v.w;
        }
        __syncthreads();
        const float* Ek = E + kc*64*DM;
        for (int k = 0; k < 64; ++k) {
            float xv = Xt[k][t];
            const float* Er = Ek + k*DM;      // uniform -> s_load
            #pragma unroll
            for (int d = 0; d < DM; ++d) acc[d] = fmaf(xv, Er[d], acc[d]);
        }
    }
    float4* out4 = (float4*)(ff + (rbase + t)*DM);
    #pragma unroll
    for (int i = 0; i < 16; ++i)
        out4[i] = make_float4(acc[4*i], acc[4*i+1], acc[4*i+2], acc[4*i+3]);
}

// ---------------- Kernel C: LSTM ----------------
// grid 2048, 512 threads; block owns 4 sequences (same b, 4 consecutive o).
// Thread: j2 = t&127 -> columns j2 and j2+128; kq = t>>7 -> quarter of combined K=128
// (kq 0,1 = ff/Wi1 halves, kq 2,3 = h/Wh halves). 64 weight VGPRs/thread, 2 barriers/step.
__global__ __launch_bounds__(512) void lstm_kernel(const float* __restrict__ ff,
                                                   const float* __restrict__ gz,
                                                   const float* __restrict__ Wi,
                                                   const float* __restrict__ Wh,
                                                   float* __restrict__ h_last,
                                                   float* __restrict__ hsum,
                                                   float* __restrict__ hsq)
{
    __shared__ __align__(16) float h_lds[4*DM];
    __shared__ __align__(16) float ff_lds[4*DM];
    __shared__ __align__(16) float zp[4][4][256];   // [kq][s][col], 16 KB
    int t = threadIdx.x;
    int j2 = t & 127;
    int kq = t >> 7;            // wave-uniform
    int bo_base = blockIdx.x * 4;
    int b = bo_base >> 8;
    int o_base = bo_base & 255;

    float w0[32], w1[32];
    if (kq < 2) {
        const float4* s0 = (const float4*)(Wi + j2*128 + kq*32);
        const float4* s1 = (const float4*)(Wi + (j2+128)*128 + kq*32);
        #pragma unroll
        for (int q = 0; q < 8; ++q) { float4 v = s0[q]; w0[4*q]=v.x; w0[4*q+1]=v.y; w0[4*q+2]=v.z; w0[4*q+3]=v.w; }
        #pragma unroll
        for (int q = 0; q < 8; ++q) { float4 v = s1[q]; w1[4*q]=v.x; w1[4*q+1]=v.y; w1[4*q+2]=v.z; w1[4*q+3]=v.w; }
    } else {
        const float4* s0 = (const float4*)(Wh + j2*64 + (kq-2)*32);
        const float4* s1 = (const float4*)(Wh + (j2+128)*64 + (kq-2)*32);
        #pragma unroll
        for (int q = 0; q < 8; ++q) { float4 v = s0[q]; w0[4*q]=v.x; w0[4*q+1]=v.y; w0[4*q+2]=v.z; w0[4*q+3]=v.w; }
        #pragma unroll
        for (int q = 0; q < 8; ++q) { float4 v = s1[q]; w1[4*q]=v.x; w1[4*q+1]=v.y; w1[4*q+2]=v.z; w1[4*q+3]=v.w; }
    }

    int s2 = t >> 6, d2 = t & 63;       // valid under t<256 guards
    float gzv[4] = {0,0,0,0};
    float ffv = 0.f;
    if (t < 256) {
        #pragma unroll
        for (int g = 0; g < 4; ++g) gzv[g] = gz[(o_base + s2)*OO + g*64 + d2];
        ffv = ff[((long)(b*LL + 0)*OO + o_base)*DM + t];   // 4 seqs x 64 contiguous
        h_lds[t] = 0.f;
    }
    float c = 0.f, sum_r = 0.f, sq_r = 0.f;

    const float* act_base = (kq < 2) ? (ff_lds + (kq & 1)*32) : (h_lds + (kq & 1)*32);

    for (int step = 0; step < LL; ++step) {
        if (t < 256) ff_lds[t] = ffv;
        __syncthreads();                           // h(step-1) ready + ff(step) ready
        // phase 1: partial z for 2 columns x 4 seqs
        #pragma unroll
        for (int s = 0; s < 4; ++s) {
            const float4* a4 = (const float4*)(act_base + s*DM);
            float p0 = 0.f, p1 = 0.f;
            #pragma unroll
            for (int q = 0; q < 8; ++q) {
                float4 av = a4[q];                 // wave-uniform broadcast
                p0 += av.x*w0[4*q] + av.y*w0[4*q+1] + av.z*w0[4*q+2] + av.w*w0[4*q+3];
                p1 += av.x*w1[4*q] + av.y*w1[4*q+1] + av.z*w1[4*q+2] + av.w*w1[4*q+3];
            }
            zp[kq][s][j2]       = p0;
            zp[kq][s][j2 + 128] = p1;
        }
        if (t < 256 && step < LL-1)
            ffv = ff[((long)(b*LL + step + 1)*OO + o_base)*DM + t];
        __syncthreads();                           // z partials ready
        // phase 2: gates (t<256 -> cell (s2,d2))
        if (t < 256) {
            float z[4];
            #pragma unroll
            for (int g = 0; g < 4; ++g) {
                int col = g*64 + d2;
                z[g] = gzv[g] + zp[0][s2][col] + zp[1][s2][col] + zp[2][s2][col] + zp[3][s2][col];
            }
            float ig = sigmoid_f(z[0]);
            float fg = sigmoid_f(z[1]);
            float gg = tanh_f(z[2]);
            float og = sigmoid_f(z[3]);
            c = fg*c + ig*gg;
            float h = og * tanh_f(c);
            h_lds[t] = h;
            sum_r += h; sq_r += h*h;
            if (step == LL-1) h_last[(bo_base + s2)*DM + d2] = h;
        }
    }
    __syncthreads();
    if (t < 256) { zp[0][0][t] = sum_r; zp[0][1][t] = sq_r; }
    __syncthreads();
    if (t < 64) {
        float s0 = zp[0][0][t] + zp[0][0][64+t] + zp[0][0][128+t] + zp[0][0][192+t];
        float q0 = zp[0][1][t] + zp[0][1][64+t] + zp[0][1][128+t] + zp[0][1][192+t];
        atomicAdd(&hsum[t], s0);
        atomicAdd(&hsq[t], q0);
    }
}

// ---------------- Kernel D: LN + v + lv + out ----------------
// grid 512 (b = blk>>4, og = blk&15), 256 threads.
__global__ __launch_bounds__(256) void final_kernel(const float* __restrict__ h_last,
                                                    const float* __restrict__ hsum,
                                                    const float* __restrict__ hsq,
                                                    const float* __restrict__ gamma,
                                                    const float* __restrict__ beta,
                                                    const float* __restrict__ Wl,
                                                    const float* __restrict__ bl,
                                                    float* __restrict__ out)
{
    __shared__ float vlds[OO][68];     // normalized v, stride 68 (16B-aligned rows)
    __shared__ float lv[16][DM];
    __shared__ float mrs[3][DM];       // mean, rstd*gamma, beta
    int t = threadIdx.x;
    int b = blockIdx.x >> 4, og = blockIdx.x & 15;
    if (t < DM) {
        float m = hsum[t] * (1.0f/131072.0f);
        float var = hsq[t] * (1.0f/131072.0f) - m*m;
        mrs[0][t] = m;
        mrs[1][t] = rsqrtf(var + 1e-5f) * gamma[t];
        mrs[2][t] = beta[t];
    }
    __syncthreads();
    {
        int d0 = (t & 15) * 4;         // same d-quad for all 16 row-groups
        float4 m4 = *(const float4*)&mrs[0][d0];
        float4 r4 = *(const float4*)&mrs[1][d0];
        float4 b4 = *(const float4*)&mrs[2][d0];
        const float4* hb = (const float4*)(h_last + (long)b*OO*DM);
        #pragma unroll
        for (int i = 0; i < 16; ++i) {
            int f4 = i*256 + t;
            float4 v = hb[f4];
            int o = f4 >> 4;
            float4 nv;
            nv.x = (v.x - m4.x)*r4.x + b4.x;
            nv.y = (v.y - m4.y)*r4.y + b4.y;
            nv.z = (v.z - m4.z)*r4.z + b4.z;
            nv.w = (v.w - m4.w)*r4.w + b4.w;
            *(float4*)&vlds[o][d0] = nv;
        }
    }
    __syncthreads();
    {   // lv rows for this block's 16 o-rows: thread (oo = t>>4, e0 = (t&15)*4)
        int oo = t >> 4;
        int e0 = (t & 15) * 4;
        int o = og*16 + oo;
        float a0 = bl[e0], a1 = bl[e0+1], a2 = bl[e0+2], a3 = bl[e0+3];
        #pragma unroll
        for (int q = 0; q < 16; ++q) {
            float4 vv = *(const float4*)&vlds[o][4*q];
            float4 wa = *(const float4*)&Wl[(e0  )*DM + 4*q];
            float4 wb = *(const float4*)&Wl[(e0+1)*DM + 4*q];
            float4 wc = *(const float4*)&Wl[(e0+2)*DM + 4*q];
            float4 wd = *(const float4*)&Wl[(e0+3)*DM + 4*q];
            a0 += vv.x*wa.x + vv.y*wa.y + vv.z*wa.z + vv.w*wa.w;
            a1 += vv.x*wb.x + vv.y*wb.y + vv.z*wb.z + vv.w*wb.w;
            a2 += vv.x*wc.x + vv.y*wc.y + vv.z*wc.z + vv.w*wc.w;
            a3 += vv.x*wd.x + vv.y*wd.y + vv.z*wd.z + vv.w*wd.w;
        }
        lv[oo][e0] = a0; lv[oo][e0+1] = a1; lv[oo][e0+2] = a2; lv[oo][e0+3] = a3;
    }
    __syncthreads();
    {   // out: thread t owns column d=t; v-row in registers, lv broadcast
        float4 vr[16];
        #pragma unroll
        for (int q = 0; q < 16; ++q) vr[q] = *(const float4*)&vlds[t][4*q];
        float* ob = out + ((long)b*OO + og*16)*OO;
        #pragma unroll
        for (int oo = 0; oo < 16; ++oo) {
            float acc = 0.f;
            #pragma unroll
            for (int q = 0; q < 16; ++q) {
                float4 lvv = *(const float4*)&lv[oo][4*q];
                acc += lvv.x*vr[q].x + lvv.y*vr[q].y + lvv.z*vr[q].z + lvv.w*vr[q].w;
            }
            ob[oo*OO + t] = acc;
        }
    }
}

extern "C" void kernel_launch(void* const* d_in, const int* in_sizes, int n_in,
                              void* d_out, int out_size, void* d_ws, size_t ws_size,
                              hipStream_t stream) {
    const float* X     = (const float*)d_in[0];
    const float* dis   = (const float*)d_in[1];
    const float* E     = (const float*)d_in[2];
    const float* Wi    = (const float*)d_in[3];
    const float* Wh    = (const float*)d_in[4];
    const float* bi    = (const float*)d_in[5];
    const float* bh    = (const float*)d_in[6];
    const float* gamma = (const float*)d_in[7];
    const float* beta  = (const float*)d_in[8];
    const float* Wl    = (const float*)d_in[9];
    const float* bl    = (const float*)d_in[10];
    float* out = (float*)d_out;

    char* ws = (char*)d_ws;
    float* gz   = (float*)(ws);                               // 256 KB
    float* ff   = (float*)(ws + 262144);                      // 33.5 MB
    float* hl   = (float*)(ws + 262144 + 33554432);           // 2 MB
    float* hsum = (float*)(ws + 262144 + 33554432 + 2097152);
    float* hsq  = hsum + 64;

    hipMemsetAsync(hsum, 0, 2*64*sizeof(float), stream);
    geo_kernel<<<256, 256, 0, stream>>>(dis, E, Wi, bi, bh, gz);
    ff_kernel<<<512, 256, 0, stream>>>(X, E, ff);
    lstm_kernel<<<2048, 512, 0, stream>>>(ff, gz, Wi, Wh, hl, hsum, hsq);
    final_kernel<<<512, 256, 0, stream>>>(hl, hsum, hsq, gamma, beta, Wl, bl, out);
}